// Round 10
// baseline (67.511 us; speedup 1.0000x reference)
//
#include <hip/hip_runtime.h>
#include <hip/hip_bf16.h>
#include <stdint.h>

#define VOCAB 200000
#define EDIM 128
#define NTREES 2048
#define KNODES 511
#define PROJ_GRID 1024

typedef __attribute__((ext_vector_type(4))) float f32x4;
typedef __attribute__((ext_vector_type(2))) float f32x2;
typedef __attribute__((ext_vector_type(8))) short s16x8;
typedef __attribute__((ext_vector_type(8))) unsigned short u16x8;

#define AS1 __attribute__((address_space(1)))
#define AS3 __attribute__((address_space(3)))

__device__ __forceinline__ unsigned short f2bf(float x) {
  unsigned u = __builtin_bit_cast(unsigned, x);
  return (unsigned short)((u + 0x7fffu + ((u >> 16) & 1u)) >> 16);  // RNE
}
__device__ __forceinline__ float bf2f(unsigned short h) {
  unsigned u = ((unsigned)h) << 16;
  return __builtin_bit_cast(float, u);
}

// ---- manual OCP e4m3fn codec (fallback paths only) ----
__device__ __forceinline__ unsigned fp8enc(float v) {
  unsigned u = __builtin_bit_cast(unsigned, v);
  unsigned s = (u >> 24) & 0x80u;
  unsigned au = u & 0x7fffffffu;
  au = au > 0x43E00000u ? 0x43E00000u : au;
  unsigned r = au + 0x0007ffffu + ((au >> 20) & 1u);
  unsigned code = (((r >> 23) - 120u) << 3) | ((r >> 20) & 7u);
  float a = __builtin_bit_cast(float, au);
  unsigned sub = (unsigned)(int)rintf(a * 512.0f);
  unsigned c = (au < 0x3C800000u) ? sub : code;
  return c | s;
}
__device__ __forceinline__ float fp8dec(unsigned b) {
  unsigned e = (b >> 3) & 15u, m = b & 7u;
  float n = __builtin_bit_cast(float, ((e + 120u) << 23) | (m << 20));
  float sv = (float)(int)m * 0.001953125f;
  float v = e ? n : sv;
  return (b & 0x80u) ? -v : v;
}

__device__ __forceinline__ unsigned enc4(float a, float b, float c, float d) {
#if __has_builtin(__builtin_amdgcn_cvt_pk_fp8_f32)
  int pk = 0;
  pk = __builtin_amdgcn_cvt_pk_fp8_f32(a, b, pk, false);
  pk = __builtin_amdgcn_cvt_pk_fp8_f32(c, d, pk, true);
  return (unsigned)pk;
#else
  return fp8enc(a) | (fp8enc(b) << 8) | (fp8enc(c) << 16) | (fp8enc(d) << 24);
#endif
}

__device__ __forceinline__ void dec8(uint2 v, float* o) {
#if __has_builtin(__builtin_amdgcn_cvt_pk_f32_fp8)
  f32x2 a = __builtin_amdgcn_cvt_pk_f32_fp8(v.x, false);
  f32x2 b = __builtin_amdgcn_cvt_pk_f32_fp8(v.x, true);
  f32x2 c = __builtin_amdgcn_cvt_pk_f32_fp8(v.y, false);
  f32x2 d = __builtin_amdgcn_cvt_pk_f32_fp8(v.y, true);
  o[0] = a[0]; o[1] = a[1]; o[2] = b[0]; o[3] = b[1];
  o[4] = c[0]; o[5] = c[1]; o[6] = d[0]; o[7] = d[1];
#else
#pragma unroll
  for (int i = 0; i < 4; ++i) o[i] = fp8dec((v.x >> (8 * i)) & 0xFFu);
#pragma unroll
  for (int i = 0; i < 4; ++i) o[4 + i] = fp8dec((v.y >> (8 * i)) & 0xFFu);
#endif
}

__device__ __forceinline__ s16x8 cvt8(f32x4 a, f32x4 b) {
  u16x8 t;
#pragma unroll
  for (int i = 0; i < 4; ++i)
    t[i] = __builtin_bit_cast(unsigned short, __float2bfloat16(a[i]));
#pragma unroll
  for (int i = 0; i < 4; ++i)
    t[4 + i] = __builtin_bit_cast(unsigned short, __float2bfloat16(b[i]));
  return __builtin_bit_cast(s16x8, t);
}

// ---------------- Kernel 0: one-shot W/bias prep, fragment-major ----------------
// WTb2 chunk c = fr*64 + lane (fr = ks*8+nt, lane = q*16+cl):
//   8 bf16 = W[ks*32+q*8+j][nt*16+cl] * 64, j=0..7.
__global__ __launch_bounds__(256) void wprep_kernel(
    const float* __restrict__ W, const float* __restrict__ b,
    unsigned short* __restrict__ WTb2, float* __restrict__ bsc) {
  int c = blockIdx.x * 256 + threadIdx.x;   // 0..2047
  if (c < 2048) {
    int lane = c & 63, fr = c >> 6;
    int ks = fr >> 3, nt = fr & 7, q = lane >> 4, cl = lane & 15;
    u16x8 t;
#pragma unroll
    for (int j = 0; j < 8; ++j)
      t[j] = f2bf(W[(ks * 32 + q * 8 + j) * EDIM + nt * 16 + cl] * 64.0f);
    *(u16x8*)(WTb2 + c * 8) = t;
  }
  if (c < EDIM) bsc[c] = b[c] * 64.0f;
}

// ---------------- Kernel 1: T8[v][d] = fp8( 64*(emb[v,:]@W[:,d] + b[d]) ) ----------------
// v8: W in LDS (ds_read -> no vmcnt pollution); emb software-pipelined in regs
// (issue t+1's 8 loads before t's MFMA burst -> compiler emits counted vmcnt).
// Opaque zero offset defeats loop-invariant hoisting of the 32 W fragments.
__global__ __launch_bounds__(256, 3) void proj_kernel(
    const float* __restrict__ emb, const unsigned short* __restrict__ WTb2,
    const float* __restrict__ bsc, unsigned char* __restrict__ T8) {
  __shared__ unsigned short WL[2048 * 8];   // 32 KiB, fragment-major (frag*1024B + lane*16B)
  __shared__ float LB[EDIM];                // 512 B bias

  const int tid = threadIdx.x;
  const int wv = tid >> 6, lane = tid & 63;
  const int q = lane >> 4, cl = lane & 15;

  // --- stage W into LDS: 8 x 1KB DMA per wave, linear dest ---
#pragma unroll
  for (int i = 0; i < 8; ++i) {
    const char* src = (const char*)WTb2 + wv * 8192 + i * 1024 + lane * 16;
    char* dst = (char*)WL + wv * 8192 + i * 1024;
    __builtin_amdgcn_global_load_lds((const AS1 unsigned int*)src,
                                     (AS3 unsigned int*)dst, 16, 0, 0);
  }
  if (tid < EDIM) LB[tid] = bsc[tid];
  __syncthreads();   // drains staging DMA (compiler emits vmcnt(0) lgkmcnt(0))

  const int NTb = VOCAB / 64;   // 3125 block-tiles of 64 rows

  int bt = blockIdx.x;
  const float* rp = emb + ((long)bt * 64 + wv * 16 + cl) * EDIM + q * 8;
  f32x4 ea[4], eb[4];
#pragma unroll
  for (int ks = 0; ks < 4; ++ks) {          // prologue: tile bt's 8 loads
    ea[ks] = *(const f32x4*)(rp + ks * 32);
    eb[ks] = *(const f32x4*)(rp + ks * 32 + 4);
  }

  for (;;) {
    const int btn = bt + PROJ_GRID;

    // consume emb regs first (compiler waits counted vmcnt here)
    s16x8 ef[4];
#pragma unroll
    for (int ks = 0; ks < 4; ++ks) ef[ks] = cvt8(ea[ks], eb[ks]);

    if (btn < NTb) {                        // issue NEXT tile's loads now
      const float* rpn = emb + ((long)btn * 64 + wv * 16 + cl) * EDIM + q * 8;
#pragma unroll
      for (int ks = 0; ks < 4; ++ks) {
        ea[ks] = *(const f32x4*)(rpn + ks * 32);
        eb[ks] = *(const f32x4*)(rpn + ks * 32 + 4);
      }
    }

    // opaque zero offset: stops hoisting of W/bias LDS reads out of the loop
    unsigned wo = 0;
    asm volatile("" : "+v"(wo));
    const char* wl = (const char*)WL + wo;
    const char* lb = (const char*)LB + wo;

    f32x4 acc[8];
#pragma unroll
    for (int nt = 0; nt < 8; ++nt) acc[nt] = (f32x4){0.f, 0.f, 0.f, 0.f};
#pragma unroll
    for (int ks = 0; ks < 4; ++ks) {
#pragma unroll
      for (int nt = 0; nt < 8; ++nt) {
        s16x8 wf = *(const s16x8*)(wl + (ks * 8 + nt) * 1024 + lane * 16);
        acc[nt] = __builtin_amdgcn_mfma_f32_16x16x32_bf16(wf, ef[ks], acc[nt], 0, 0, 0);
      }
    }

    const long row = (long)bt * 64 + wv * 16 + cl;
#pragma unroll
    for (int nt = 0; nt < 8; ++nt) {
      const int col0 = nt * 16 + q * 4;
      f32x4 bv = *(const f32x4*)(lb + col0 * 4);
      *(unsigned*)&T8[row * EDIM + col0] =
          enc4(acc[nt][0] + bv[0], acc[nt][1] + bv[1],
               acc[nt][2] + bv[2], acc[nt][3] + bv[3]);
    }

    if (btn >= NTb) break;
    bt = btn;
  }
}

// ---------------- Kernel 2: one block = one tree, full 128-dim fp8 rows ----------------
// (unchanged — ~9 us)
__global__ __launch_bounds__(512, 4) void tree_kernel(
    const unsigned char* __restrict__ T8, const int* __restrict__ tokens,
    float* __restrict__ out) {
  __shared__ unsigned char P8[512][EDIM];          // 64 KiB
  unsigned char* lds = &P8[0][0];
  const int SOFF = 16384;
  const int MOFF = 53248;

  const int tid = threadIdx.x;
  const int tree = blockIdx.x;
  const int wv = tid >> 6, lane = tid & 63;

  const int* tk = tokens + (long)tree * KNODES;
  int toks[8];
#pragma unroll
  for (int i = 0; i < 8; ++i) {
    int node = wv * 64 + i * 8 + (lane >> 3);
    toks[i] = tk[node > 510 ? 510 : node];
  }
  const int chunk = (lane & 7) ^ ((lane >> 3) & 7);
#pragma unroll
  for (int i = 0; i < 8; ++i) {
    const unsigned char* src = T8 + (long)toks[i] * EDIM + chunk * 16;
    unsigned char* dst = &P8[wv * 64 + i * 8][0];
    __builtin_amdgcn_global_load_lds((const AS1 unsigned int*)src,
                                     (AS3 unsigned int*)dst, 16, 0, 0);
  }
  __syncthreads();

  auto ldP8 = [&](int row, int q8) -> uint2 {
    int g = q8 >> 1, h = q8 & 1;
    return *(const uint2*)(lds + row * 128 + (((g ^ (row & 7))) << 4) + h * 8);
  };
  auto saddr = [&](int slot, int q16) -> unsigned char* {
    return lds + SOFF + slot * 288 + ((q16 ^ (slot & 7)) << 4);
  };

  const int q = tid & 15;
  const int jg = tid >> 4;
  float rmax[8];
#pragma unroll
  for (int e = 0; e < 8; ++e) rmax[e] = 0.f;

  u16x8 sp7[4];
#pragma unroll
  for (int k = 0; k < 4; ++k) {
    const int p = jg + 32 * k, m = 127 + p;
    uint2 pr = ldP8(m, q);
    uint2 xr = ldP8(2 * m + 1, q);
    uint2 yr = ldP8(2 * m + 2, q);
    float pv[8], xv[8], yv[8];
    dec8(pr, pv); dec8(xr, xv); dec8(yr, yv);
#pragma unroll
    for (int e = 0; e < 8; ++e) {
      float sv = pv[e] + xv[e] + yv[e];
      rmax[e] = fmaxf(rmax[e], fmaxf(fmaxf(xv[e], yv[e]), sv));
      sp7[k][e] = f2bf(sv);
    }
  }
  __syncthreads();
#pragma unroll
  for (int k = 0; k < 4; ++k) *(u16x8*)saddr(jg + 32 * k, q) = sp7[k];
  __syncthreads();

  for (int l = 6; l >= 0; --l) {
    const int cnt = 1 << l;
    for (int p = jg; p < cnt; p += 32) {
      const int m = cnt - 1 + p;
      const int ps = p << (7 - l);
      const int c2s = ps + (1 << (6 - l));
      uint2 pr = ldP8(m, q);
      u16x8 c1 = *(const u16x8*)saddr(ps, q);
      u16x8 c2 = *(const u16x8*)saddr(c2s, q);
      float pv[8];
      dec8(pr, pv);
      u16x8 sp;
#pragma unroll
      for (int e = 0; e < 8; ++e) {
        float sv = pv[e] + bf2f(c1[e]) + bf2f(c2[e]);
        rmax[e] = fmaxf(rmax[e], sv);
        sp[e] = f2bf(sv);
      }
      *(u16x8*)saddr(ps, q) = sp;
    }
    __syncthreads();
  }

#pragma unroll
  for (int e = 0; e < 8; ++e) {
    rmax[e] = fmaxf(rmax[e], __shfl_xor(rmax[e], 16, 64));
    rmax[e] = fmaxf(rmax[e], __shfl_xor(rmax[e], 32, 64));
  }
  float* mb = (float*)(lds + MOFF);
  if (lane < 16) {
#pragma unroll
    for (int e = 0; e < 8; ++e) mb[wv * 128 + lane * 8 + e] = rmax[e];
  }
  __syncthreads();
  if (tid < 128) {
    float v = mb[tid];
#pragma unroll
    for (int w2 = 1; w2 < 8; ++w2) v = fmaxf(v, mb[w2 * 128 + tid]);
    out[(long)tree * 128 + tid] = v * 0.015625f;
  }
}

extern "C" void kernel_launch(void* const* d_in, const int* in_sizes, int n_in,
                              void* d_out, int out_size, void* d_ws, size_t ws_size,
                              hipStream_t stream) {
  const float* emb = (const float*)d_in[0];
  const float* W = (const float*)d_in[1];
  const float* b = (const float*)d_in[2];
  const int* tokens = (const int*)d_in[3];

  unsigned char* T8 = (unsigned char*)d_ws;                          // 25.6 MB
  unsigned short* WTb2 = (unsigned short*)((char*)d_ws + 25600000);  // 32 KB
  float* bsc = (float*)((char*)d_ws + 25632768);                     // 512 B
  float* out = (float*)d_out;

  wprep_kernel<<<8, 256, 0, stream>>>(W, b, WTb2, bsc);
  proj_kernel<<<PROJ_GRID, 256, 0, stream>>>(emb, WTb2, bsc, T8);
  tree_kernel<<<NTREES, 512, 0, stream>>>(T8, tokens, out);
}

// Round 11
// 64.136 us; speedup vs baseline: 1.0526x; 1.0526x over previous
//
#include <hip/hip_runtime.h>
#include <hip/hip_bf16.h>
#include <stdint.h>

#define VOCAB 200000
#define EDIM 128
#define NTREES 2048
#define KNODES 511
#define PROJ_GRID 1024

typedef __attribute__((ext_vector_type(4))) float f32x4;
typedef __attribute__((ext_vector_type(2))) float f32x2;
typedef __attribute__((ext_vector_type(8))) short s16x8;
typedef __attribute__((ext_vector_type(8))) unsigned short u16x8;
typedef __attribute__((ext_vector_type(4))) unsigned int u32x4;

#define AS1 __attribute__((address_space(1)))
#define AS3 __attribute__((address_space(3)))

__device__ __forceinline__ unsigned short f2bf(float x) {
  unsigned u = __builtin_bit_cast(unsigned, x);
  return (unsigned short)((u + 0x7fffu + ((u >> 16) & 1u)) >> 16);  // RNE
}
__device__ __forceinline__ float bf2f(unsigned short h) {
  unsigned u = ((unsigned)h) << 16;
  return __builtin_bit_cast(float, u);
}

// ---- manual OCP e4m3fn codec (fallback paths only) ----
__device__ __forceinline__ unsigned fp8enc(float v) {
  unsigned u = __builtin_bit_cast(unsigned, v);
  unsigned s = (u >> 24) & 0x80u;
  unsigned au = u & 0x7fffffffu;
  au = au > 0x43E00000u ? 0x43E00000u : au;
  unsigned r = au + 0x0007ffffu + ((au >> 20) & 1u);
  unsigned code = (((r >> 23) - 120u) << 3) | ((r >> 20) & 7u);
  float a = __builtin_bit_cast(float, au);
  unsigned sub = (unsigned)(int)rintf(a * 512.0f);
  unsigned c = (au < 0x3C800000u) ? sub : code;
  return c | s;
}
__device__ __forceinline__ float fp8dec(unsigned b) {
  unsigned e = (b >> 3) & 15u, m = b & 7u;
  float n = __builtin_bit_cast(float, ((e + 120u) << 23) | (m << 20));
  float sv = (float)(int)m * 0.001953125f;
  float v = e ? n : sv;
  return (b & 0x80u) ? -v : v;
}

__device__ __forceinline__ unsigned enc4(float a, float b, float c, float d) {
#if __has_builtin(__builtin_amdgcn_cvt_pk_fp8_f32)
  int pk = 0;
  pk = __builtin_amdgcn_cvt_pk_fp8_f32(a, b, pk, false);
  pk = __builtin_amdgcn_cvt_pk_fp8_f32(c, d, pk, true);
  return (unsigned)pk;
#else
  return fp8enc(a) | (fp8enc(b) << 8) | (fp8enc(c) << 16) | (fp8enc(d) << 24);
#endif
}

__device__ __forceinline__ void dec8(uint2 v, float* o) {
#if __has_builtin(__builtin_amdgcn_cvt_pk_f32_fp8)
  f32x2 a = __builtin_amdgcn_cvt_pk_f32_fp8(v.x, false);
  f32x2 b = __builtin_amdgcn_cvt_pk_f32_fp8(v.x, true);
  f32x2 c = __builtin_amdgcn_cvt_pk_f32_fp8(v.y, false);
  f32x2 d = __builtin_amdgcn_cvt_pk_f32_fp8(v.y, true);
  o[0] = a[0]; o[1] = a[1]; o[2] = b[0]; o[3] = b[1];
  o[4] = c[0]; o[5] = c[1]; o[6] = d[0]; o[7] = d[1];
#else
#pragma unroll
  for (int i = 0; i < 4; ++i) o[i] = fp8dec((v.x >> (8 * i)) & 0xFFu);
#pragma unroll
  for (int i = 0; i < 4; ++i) o[4 + i] = fp8dec((v.y >> (8 * i)) & 0xFFu);
#endif
}

__device__ __forceinline__ s16x8 cvt8(f32x4 a, f32x4 b) {
  u16x8 t;
#pragma unroll
  for (int i = 0; i < 4; ++i)
    t[i] = __builtin_bit_cast(unsigned short, __float2bfloat16(a[i]));
#pragma unroll
  for (int i = 0; i < 4; ++i)
    t[4 + i] = __builtin_bit_cast(unsigned short, __float2bfloat16(b[i]));
  return __builtin_bit_cast(s16x8, t);
}

// ---------------- Kernel 0: one-shot W/bias prep, fragment-major ----------------
__global__ __launch_bounds__(256) void wprep_kernel(
    const float* __restrict__ W, const float* __restrict__ b,
    unsigned short* __restrict__ WTb2, float* __restrict__ bsc) {
  int c = blockIdx.x * 256 + threadIdx.x;   // 0..2047
  if (c < 2048) {
    int lane = c & 63, fr = c >> 6;
    int ks = fr >> 3, nt = fr & 7, q = lane >> 4, cl = lane & 15;
    u16x8 t;
#pragma unroll
    for (int j = 0; j < 8; ++j)
      t[j] = f2bf(W[(ks * 32 + q * 8 + j) * EDIM + nt * 16 + cl] * 64.0f);
    *(u16x8*)(WTb2 + c * 8) = t;
  }
  if (c < EDIM) bsc[c] = b[c] * 64.0f;
}

// ---------------- Kernel 1: T8[v][d] = fp8( 64*(emb[v,:]@W[:,d] + b[d]) ) ----------------
// v9 = v8 + LDS-staged COALESCED stores: enc4 -> per-wave stage (144B pitch) ->
// 2 x ds_read_b128 -> 2 x 1KB-contiguous global_store_dwordx4 (16x fewer
// write segments than the 4B scatter). No extra barriers (wave-private stage).
__global__ __launch_bounds__(256, 3) void proj_kernel(
    const float* __restrict__ emb, const unsigned short* __restrict__ WTb2,
    const float* __restrict__ bsc, unsigned char* __restrict__ T8) {
  __shared__ unsigned short WL[2048 * 8];   // 32 KiB, fragment-major
  __shared__ float LB[EDIM];                // 512 B bias
  __shared__ char ST[4][16 * 144];          // 9 KiB store-stage (per wave 16 rows x 144B)

  const int tid = threadIdx.x;
  const int wv = tid >> 6, lane = tid & 63;
  const int q = lane >> 4, cl = lane & 15;

  // --- stage W into LDS: 8 x 1KB DMA per wave, linear dest ---
#pragma unroll
  for (int i = 0; i < 8; ++i) {
    const char* src = (const char*)WTb2 + wv * 8192 + i * 1024 + lane * 16;
    char* dst = (char*)WL + wv * 8192 + i * 1024;
    __builtin_amdgcn_global_load_lds((const AS1 unsigned int*)src,
                                     (AS3 unsigned int*)dst, 16, 0, 0);
  }
  if (tid < EDIM) LB[tid] = bsc[tid];
  __syncthreads();

  const int NTb = VOCAB / 64;   // 3125 block-tiles of 64 rows

  int bt = blockIdx.x;
  const float* rp = emb + ((long)bt * 64 + wv * 16 + cl) * EDIM + q * 8;
  f32x4 ea[4], eb[4];
#pragma unroll
  for (int ks = 0; ks < 4; ++ks) {          // prologue: tile bt's 8 loads
    ea[ks] = *(const f32x4*)(rp + ks * 32);
    eb[ks] = *(const f32x4*)(rp + ks * 32 + 4);
  }

  for (;;) {
    const int btn = bt + PROJ_GRID;

    s16x8 ef[4];
#pragma unroll
    for (int ks = 0; ks < 4; ++ks) ef[ks] = cvt8(ea[ks], eb[ks]);

    if (btn < NTb) {                        // issue NEXT tile's loads now
      const float* rpn = emb + ((long)btn * 64 + wv * 16 + cl) * EDIM + q * 8;
#pragma unroll
      for (int ks = 0; ks < 4; ++ks) {
        ea[ks] = *(const f32x4*)(rpn + ks * 32);
        eb[ks] = *(const f32x4*)(rpn + ks * 32 + 4);
      }
    }

    // opaque zero offset: stops hoisting of W/bias LDS reads out of the loop
    unsigned wo = 0;
    asm volatile("" : "+v"(wo));
    const char* wl = (const char*)WL + wo;
    const char* lb = (const char*)LB + wo;

    f32x4 acc[8];
#pragma unroll
    for (int nt = 0; nt < 8; ++nt) acc[nt] = (f32x4){0.f, 0.f, 0.f, 0.f};
#pragma unroll
    for (int ks = 0; ks < 4; ++ks) {
#pragma unroll
      for (int nt = 0; nt < 8; ++nt) {
        s16x8 wf = *(const s16x8*)(wl + (ks * 8 + nt) * 1024 + lane * 16);
        acc[nt] = __builtin_amdgcn_mfma_f32_16x16x32_bf16(wf, ef[ks], acc[nt], 0, 0, 0);
      }
    }

    // ---- stage: lane's 8 packed u32 -> [row=cl][u32 col=nt*4+q], pitch 144B ----
    char* sw = &ST[wv][0] + cl * 144;
#pragma unroll
    for (int nt = 0; nt < 8; ++nt) {
      f32x4 bv = *(const f32x4*)(lb + (nt * 16 + q * 4) * 4);
      unsigned pk = enc4(acc[nt][0] + bv[0], acc[nt][1] + bv[1],
                         acc[nt][2] + bv[2], acc[nt][3] + bv[3]);
      *(unsigned*)(sw + (nt * 4 + q) * 4) = pk;
    }

    // ---- drain: 2 x (ds_read_b128 + 1KB-contiguous wave store) ----
    const long tb8 = ((long)bt * 64 + wv * 16) * EDIM;   // byte base of wave's 16 rows
#pragma unroll
    for (int j = 0; j < 2; ++j) {
      const int slot = j * 64 + lane;                    // 16B chunk id 0..127
      const int r = slot >> 3, c16 = slot & 7;
      u32x4 v = *(const u32x4*)(&ST[wv][0] + r * 144 + c16 * 16);
      *(u32x4*)&T8[tb8 + slot * 16] = v;
    }

    if (btn >= NTb) break;
    bt = btn;
  }
}

// ---------------- Kernel 2: one block = one tree, full 128-dim fp8 rows ----------------
// (unchanged — ~9 us)
__global__ __launch_bounds__(512, 4) void tree_kernel(
    const unsigned char* __restrict__ T8, const int* __restrict__ tokens,
    float* __restrict__ out) {
  __shared__ unsigned char P8[512][EDIM];          // 64 KiB
  unsigned char* lds = &P8[0][0];
  const int SOFF = 16384;
  const int MOFF = 53248;

  const int tid = threadIdx.x;
  const int tree = blockIdx.x;
  const int wv = tid >> 6, lane = tid & 63;

  const int* tk = tokens + (long)tree * KNODES;
  int toks[8];
#pragma unroll
  for (int i = 0; i < 8; ++i) {
    int node = wv * 64 + i * 8 + (lane >> 3);
    toks[i] = tk[node > 510 ? 510 : node];
  }
  const int chunk = (lane & 7) ^ ((lane >> 3) & 7);
#pragma unroll
  for (int i = 0; i < 8; ++i) {
    const unsigned char* src = T8 + (long)toks[i] * EDIM + chunk * 16;
    unsigned char* dst = &P8[wv * 64 + i * 8][0];
    __builtin_amdgcn_global_load_lds((const AS1 unsigned int*)src,
                                     (AS3 unsigned int*)dst, 16, 0, 0);
  }
  __syncthreads();

  auto ldP8 = [&](int row, int q8) -> uint2 {
    int g = q8 >> 1, h = q8 & 1;
    return *(const uint2*)(lds + row * 128 + (((g ^ (row & 7))) << 4) + h * 8);
  };
  auto saddr = [&](int slot, int q16) -> unsigned char* {
    return lds + SOFF + slot * 288 + ((q16 ^ (slot & 7)) << 4);
  };

  const int q = tid & 15;
  const int jg = tid >> 4;
  float rmax[8];
#pragma unroll
  for (int e = 0; e < 8; ++e) rmax[e] = 0.f;

  u16x8 sp7[4];
#pragma unroll
  for (int k = 0; k < 4; ++k) {
    const int p = jg + 32 * k, m = 127 + p;
    uint2 pr = ldP8(m, q);
    uint2 xr = ldP8(2 * m + 1, q);
    uint2 yr = ldP8(2 * m + 2, q);
    float pv[8], xv[8], yv[8];
    dec8(pr, pv); dec8(xr, xv); dec8(yr, yv);
#pragma unroll
    for (int e = 0; e < 8; ++e) {
      float sv = pv[e] + xv[e] + yv[e];
      rmax[e] = fmaxf(rmax[e], fmaxf(fmaxf(xv[e], yv[e]), sv));
      sp7[k][e] = f2bf(sv);
    }
  }
  __syncthreads();
#pragma unroll
  for (int k = 0; k < 4; ++k) *(u16x8*)saddr(jg + 32 * k, q) = sp7[k];
  __syncthreads();

  for (int l = 6; l >= 0; --l) {
    const int cnt = 1 << l;
    for (int p = jg; p < cnt; p += 32) {
      const int m = cnt - 1 + p;
      const int ps = p << (7 - l);
      const int c2s = ps + (1 << (6 - l));
      uint2 pr = ldP8(m, q);
      u16x8 c1 = *(const u16x8*)saddr(ps, q);
      u16x8 c2 = *(const u16x8*)saddr(c2s, q);
      float pv[8];
      dec8(pr, pv);
      u16x8 sp;
#pragma unroll
      for (int e = 0; e < 8; ++e) {
        float sv = pv[e] + bf2f(c1[e]) + bf2f(c2[e]);
        rmax[e] = fmaxf(rmax[e], sv);
        sp[e] = f2bf(sv);
      }
      *(u16x8*)saddr(ps, q) = sp;
    }
    __syncthreads();
  }

#pragma unroll
  for (int e = 0; e < 8; ++e) {
    rmax[e] = fmaxf(rmax[e], __shfl_xor(rmax[e], 16, 64));
    rmax[e] = fmaxf(rmax[e], __shfl_xor(rmax[e], 32, 64));
  }
  float* mb = (float*)(lds + MOFF);
  if (lane < 16) {
#pragma unroll
    for (int e = 0; e < 8; ++e) mb[wv * 128 + lane * 8 + e] = rmax[e];
  }
  __syncthreads();
  if (tid < 128) {
    float v = mb[tid];
#pragma unroll
    for (int w2 = 1; w2 < 8; ++w2) v = fmaxf(v, mb[w2 * 128 + tid]);
    out[(long)tree * 128 + tid] = v * 0.015625f;
  }
}

extern "C" void kernel_launch(void* const* d_in, const int* in_sizes, int n_in,
                              void* d_out, int out_size, void* d_ws, size_t ws_size,
                              hipStream_t stream) {
  const float* emb = (const float*)d_in[0];
  const float* W = (const float*)d_in[1];
  const float* b = (const float*)d_in[2];
  const int* tokens = (const int*)d_in[3];

  unsigned char* T8 = (unsigned char*)d_ws;                          // 25.6 MB
  unsigned short* WTb2 = (unsigned short*)((char*)d_ws + 25600000);  // 32 KB
  float* bsc = (float*)((char*)d_ws + 25632768);                     // 512 B
  float* out = (float*)d_out;

  wprep_kernel<<<8, 256, 0, stream>>>(W, b, WTb2, bsc);
  proj_kernel<<<PROJ_GRID, 256, 0, stream>>>(emb, WTb2, bsc, T8);
  tree_kernel<<<NTREES, 512, 0, stream>>>(T8, tokens, out);
}